// Round 3
// baseline (498.062 us; speedup 1.0000x reference)
//
#include <hip/hip_runtime.h>
#include <math.h>

#define BB 16
#define NN 1024
#define VV 4096
#define TT 8
#define NG (BB*TT)   // 128 groups
#define KMAX 124     // max group size; Binomial(1024,1/16): mean 64, sigma 7.75 -> ~8 sigma
#define LSEROWS 8    // rows per lse block
#define NBLK (NG + (BB*NN)/LSEROWS)   // total blocks in k_main

__device__ __forceinline__ float wave_sum(float v){
  #pragma unroll
  for (int off = 32; off; off >>= 1) v += __shfl_down(v, off);
  return v;
}

// monotone float <-> uint key (finite values)
__device__ __forceinline__ unsigned fkey(float f){
  unsigned b = __float_as_uint(f);
  return b ^ ((unsigned)((int)b >> 31) | 0x80000000u);
}
__device__ __forceinline__ float inv_fkey(unsigned u){
  unsigned b = (u & 0x80000000u) ? (u ^ 0x80000000u) : ~u;
  return __uint_as_float(b);
}

// 64-lane min-reduction via DPP (VALU-only). Result valid in lane 63.
__device__ __forceinline__ unsigned dpp_min64(unsigned x){
  unsigned t;
  t = (unsigned)__builtin_amdgcn_update_dpp(-1, (int)x, 0x111, 0xF, 0xF, false); x = x < t ? x : t;
  t = (unsigned)__builtin_amdgcn_update_dpp(-1, (int)x, 0x112, 0xF, 0xF, false); x = x < t ? x : t;
  t = (unsigned)__builtin_amdgcn_update_dpp(-1, (int)x, 0x114, 0xF, 0xF, false); x = x < t ? x : t;
  t = (unsigned)__builtin_amdgcn_update_dpp(-1, (int)x, 0x118, 0xF, 0xF, false); x = x < t ? x : t;
  t = (unsigned)__builtin_amdgcn_update_dpp(-1, (int)x, 0x142, 0xF, 0xF, false); x = x < t ? x : t;
  t = (unsigned)__builtin_amdgcn_update_dpp(-1, (int)x, 0x143, 0xF, 0xF, false); x = x < t ? x : t;
  return x;
}

// ---- lse helpers: statically-indexed register row buffer (rule #20 safe) ----
__device__ __forceinline__ void lse_load(const float4* __restrict__ x, int lane,
                                         float4 (&v)[16]){
  #pragma unroll
  for (int i = 0; i < 16; i++) v[i] = x[lane + 64*i];   // coalesced, 16 in flight
}
__device__ __forceinline__ float lse_reduce(const float4 (&v)[16]){
  float m = -INFINITY;
  #pragma unroll
  for (int i = 0; i < 16; i++)
    m = fmaxf(m, fmaxf(fmaxf(v[i].x, v[i].y), fmaxf(v[i].z, v[i].w)));
  #pragma unroll
  for (int off = 32; off; off >>= 1) m = fmaxf(m, __shfl_xor(m, off));
  float s = 0.f;
  #pragma unroll
  for (int i = 0; i < 16; i++)
    s += __expf(v[i].x - m) + __expf(v[i].y - m)
       + __expf(v[i].z - m) + __expf(v[i].w - m);
  #pragma unroll
  for (int off = 32; off; off >>= 1) s += __shfl_xor(s, off);
  return m + __logf(s);
}

// ---- block epilogue: device-scope accumulate + last-block finalize ----
// loss = (sum lse - sum_g gval) / sum_g k. Accumulators in d_ws, zeroed by a
// captured hipMemsetAsync each iteration (d_ws is harness-poisoned).
__device__ __forceinline__ void finish_block(double* sd, double* sg, int* si,
                                             unsigned* cnt, float* out, int lane){
  if (lane != 0) return;
  __threadfence();                               // release my atomics
  unsigned prev = atomicAdd(cnt, 1u);
  if (prev == (unsigned)NBLK - 1u){
    double a = atomicAdd(sd, 0.0);               // coherent reads
    double b = atomicAdd(sg, 0.0);
    int    c = atomicAdd(si, 0);
    out[0] = (float)((a - b) / (double)c);
  }
}

// ---------------------------------------------------------------------------
// Fused kernel: blocks [0, NG) run the per-group LAP (Jonker-Volgenant, one
// wave per block); blocks [NG, NBLK) compute LSEROWS per-row logsumexps over
// V=4096 (register double-buffer). jv is the binding span (R1/R2 evidence);
// lse hides underneath. This round: redundant single-wave barriers removed
// from the jv hot loops (same-wave DS pipe is in-order), Cm stored as
// float2[row][64] so each lane's two columns are one ds_read_b64, 16-deep
// gather pipeline, and atomic-reduction epilogue (no k_final kernel).
__global__ __launch_bounds__(64) void k_main(const float* __restrict__ logits,
                                             const int* __restrict__ types,
                                             const int* __restrict__ gt,
                                             const unsigned char* __restrict__ raw,
                                             double* __restrict__ sd_acc,
                                             double* __restrict__ sg_acc,
                                             int* __restrict__ si_acc,
                                             unsigned* __restrict__ cnt,
                                             float* __restrict__ out){
  int lane = threadIdx.x;

  if (blockIdx.x >= NG){
    // ------------------------- LSE path -------------------------
    int rbase = (blockIdx.x - NG) * LSEROWS;
    uchar4 pv = ((const uchar4*)raw)[lane];            // bytes 0..255 of mask
    bool bool_layout = (__ballot((pv.y | pv.z | pv.w) != 0) != 0ull);
    const int* rawi = (const int*)raw;
    unsigned mb = 0;                                    // wave-uniform bitmask
    #pragma unroll
    for (int r = 0; r < LSEROWS; r++){
      int mv = bool_layout ? (int)raw[rbase + r] : rawi[rbase + r];
      mb |= (mv != 0) ? (1u << r) : 0u;
    }
    if (mb == 0){ finish_block(sd_acc, sg_acc, si_acc, cnt, out, lane); return; }

    double lsum = 0.0;
    float4 A[16], Bf[16];                               // static indexing only
    int rA = __ffs(mb) - 1;
    unsigned rem = mb & ~(1u << rA);
    lse_load((const float4*)(logits + (size_t)(rbase + rA) * VV), lane, A);
    while (true){
      int rB = rem ? (__ffs(rem) - 1) : -1;
      if (rB >= 0){
        rem &= ~(1u << rB);
        lse_load((const float4*)(logits + (size_t)(rbase + rB) * VV), lane, Bf);
      }
      lsum += (double)lse_reduce(A);                    // waits on A only
      if (rB < 0) break;
      int rC = rem ? (__ffs(rem) - 1) : -1;
      if (rC >= 0){
        rem &= ~(1u << rC);
        lse_load((const float4*)(logits + (size_t)(rbase + rC) * VV), lane, A);
      }
      lsum += (double)lse_reduce(Bf);
      if (rC < 0) break;
      rA = rC;
    }
    if (lane == 0) atomicAdd(sd_acc, lsum);
    finish_block(sd_acc, sg_acc, si_acc, cnt, out, lane);
    return;
  }

  // ------------------------- JV / LAP path -------------------------
  // lapjv init (column reduction + 3x augmenting row reduction) + Dijkstra
  // SAP for remaining free rows. One wave per block; lane owns cols
  // {lane+1, lane+65} (1-based), stored interleaved: Cm2[row][lane] =
  // (C[row][lane], C[row][64+lane]). All phases maintain dual feasibility.
  // Single-wave block: hot-loop __syncthreads removed (DS pipe is in-order
  // per wave; compiler tracks LDS deps via lgkmcnt).
  __shared__ float2 Cm2[KMAX*64];      // 63488 B
  __shared__ float u_l[KMAX+1];        // row potentials (rows 1..k); [0] scratch
  __shared__ int   p_l[KMAX+1];        // col -> row (1-based; 0 = free)
  __shared__ int   way_l[KMAX+1];      // idx staging, then scan predecessors
  __shared__ int   rowown[KMAX];       // CR: row -> winning col (-1 free)
  __shared__ int   listA[KMAX];        // gtk staging, then free-row list
  __shared__ int   listB[KMAX];
  int g = blockIdx.x, b = g >> 3, t = g & 7;
  unsigned long long lm = (1ull << lane) - 1ull;

  // ---- inline prep: mask layout probe + ballot compaction ----
  int local = 0;
  const uchar4* r4 = (const uchar4*)raw;
  #pragma unroll
  for (int r = 0; r < 4; r++){ uchar4 u = r4[lane + 64*r]; local |= (u.y | u.z | u.w); }
  bool bool_layout = (__ballot(local != 0) != 0ull);
  const int* rawi = (const int*)raw;
  int base = 0;
  #pragma unroll
  for (int r = 0; r < NN/64; r++){
    int pos = r*64 + lane, o = b*NN + pos;
    int mv = bool_layout ? (int)raw[o] : rawi[o];
    bool pred = (types[o] == t) && (mv != 0);
    unsigned long long ball = __ballot(pred);
    int dst = base + __popcll(ball & lm);
    if (pred && dst < KMAX){ way_l[dst] = pos; listA[dst] = gt[o]; }
    base += __popcll(ball);
  }
  int k = (base > KMAX) ? KMAX : base;
  if (k == 0){
    finish_block(sd_acc, sg_acc, si_acc, cnt, out, lane);
    return;
  }

  int col0 = lane + 1, col1 = lane + 65;
  bool a0 = (col0 <= k), a1 = (col1 <= k);
  int gc0 = a0 ? listA[lane]      : 0;   // same-wave LDS: in-order DS pipe
  int gc1 = a1 ? listA[lane + 64] : 0;

  u_l[col0] = 0.f; p_l[col0] = 0;
  if (col1 <= KMAX){ u_l[col1] = 0.f; p_l[col1] = 0; }
  if (lane == 0){ u_l[0] = 0.f; p_l[0] = 0; }
  rowown[lane] = -1;
  if (lane + 64 < KMAX) rowown[lane+64] = -1;
  __syncthreads();

  // ---- staging: 16-row software pipeline (32 gathers in flight) ----
  const size_t rowbase = (size_t)b * NN;
  for (int i = 0; i < k; i += 16){
    float xs0[16], xs1[16]; int rr[16];
    #pragma unroll
    for (int s = 0; s < 16; s++){
      int r = i + s; r = (r < k) ? r : (k - 1); rr[s] = r;
      const float* q = logits + (rowbase + way_l[r]) * VV;
      xs0[s] = q[gc0]; xs1[s] = q[gc1];
    }
    #pragma unroll
    for (int s = 0; s < 16; s++)
      Cm2[rr[s]*64 + lane] = make_float2(-xs0[s], -xs1[s]);
  }
  __syncthreads();

  // ---- column reduction: v[j] = min_i C[i][j]; assign argmin row if free ----
  float v0 = 0.f, v1 = 0.f;
  int ra0 = -1, ra1 = -1;
  {
    float m0 = INFINITY, m1 = INFINITY; int rm0 = 0, rm1 = 0;
    for (int i = 0; i < k; i++){
      float2 c = Cm2[i*64 + lane];
      if (c.x < m0){ m0 = c.x; rm0 = i; }
      if (c.y < m1){ m1 = c.y; rm1 = i; }
    }
    if (a0){ v0 = m0; ra0 = rm0; }
    if (a1){ v1 = m1; ra1 = rm1; }
  }
  if (a0){ if (atomicCAS(&rowown[ra0], -1, col0) == -1) p_l[col0] = ra0 + 1; }
  if (a1){ if (atomicCAS(&rowown[ra1], -1, col1) == -1) p_l[col1] = ra1 + 1; }
  __syncthreads();

  // free-row list
  bool f0 = (lane < k)    && (rowown[lane]    == -1);
  bool f1 = (lane+64 < k) && (rowown[lane+64] == -1);
  unsigned long long B0 = __ballot(f0), B1 = __ballot(f1);
  int n0 = __popcll(B0);
  if (f0) listA[__popcll(B0 & lm)]      = lane + 1;   // rows 1-based
  if (f1) listA[n0 + __popcll(B1 & lm)] = lane + 65;
  int nCur = n0 + __popcll(B1);
  __syncthreads();

  // ---- augmenting row reduction, 3 passes (no per-row barrier: 1 wave) ----
  int* curL = listA; int* nxtL = listB;
  for (int pass = 0; pass < 3; pass++){
    int nNxt = 0;
    for (int fr = 0; fr < nCur; fr++){
      int row = curL[fr];                       // wave-uniform
      float2 rc = Cm2[(row - 1)*64 + lane];
      float rc0 = a0 ? (rc.x - v0) : INFINITY;
      float rc1 = a1 ? (rc.y - v1) : INFINITY;
      unsigned k0 = fkey(rc0), k1 = fkey(rc1);
      unsigned kk = k0 < k1 ? k0 : k1;
      unsigned m1 = (unsigned)__builtin_amdgcn_readlane((int)dpp_min64(kk), 63);
      int cand = (k0 == m1) ? col0 : ((k1 == m1) ? col1 : 0);
      unsigned long long bl1 = __ballot(cand != 0);
      int ow1 = __ffsll(bl1) - 1;
      int j1 = __builtin_amdgcn_readlane(cand, ow1);
      float u1 = inv_fkey(m1);
      unsigned k0b = (col0 == j1) ? 0xFFFFFFFFu : k0;
      unsigned k1b = (col1 == j1) ? 0xFFFFFFFFu : k1;
      unsigned kkb = k0b < k1b ? k0b : k1b;
      unsigned m2 = (unsigned)__builtin_amdgcn_readlane((int)dpp_min64(kkb), 63);
      float u2 = inv_fkey(m2);
      int jt = j1;
      if (u1 < u2){
        if (col0 == j1) v0 -= (u2 - u1);
        if (col1 == j1) v1 -= (u2 - u1);
      } else {
        int own1 = p_l[j1];
        if (own1 != 0){
          int cand2 = (k0b == m2) ? col0 : ((k1b == m2) ? col1 : 0);
          unsigned long long bl2 = __ballot(cand2 != 0);
          int ow2 = __ffsll(bl2) - 1;
          jt = __builtin_amdgcn_readlane(cand2, ow2);
        }
      }
      int iprev = p_l[jt];                      // wave-uniform
      if (lane == 0){ p_l[jt] = row; u_l[row] = u2; }
      if (iprev != 0){ if (lane == 0) nxtL[nNxt] = iprev; nNxt++; }
    }
    int* tmp = curL; curL = nxtL; nxtL = tmp;
    nCur = nNxt;
  }

  // ---- Dijkstra shortest augmenting path for remaining free rows ----
  for (int fr = 0; fr < nCur; fr++){
    int irow = curL[fr];
    int rp0 = a0 ? p_l[col0] : 0;
    int rp1 = a1 ? p_l[col1] : 0;
    float rpu0 = (rp0 > 0) ? u_l[rp0] : 0.f;
    float rpu1 = (rp1 > 0) ? u_l[rp1] : 0.f;
    float2 dini = Cm2[(irow - 1)*64 + lane];
    float dist0 = a0 ? (dini.x - v0) : INFINITY;
    float dist1 = a1 ? (dini.y - v1) : INFINITY;
    int way0 = 0, way1 = 0;
    bool used0 = false, used1 = false;
    int j_end; float delta_end;
    while (true){
      unsigned q0 = (a0 && !used0) ? ((fkey(dist0) & 0xFFFFFF80u) | (unsigned)(col0-1)) : 0xFFFFFFFFu;
      unsigned q1 = (a1 && !used1) ? ((fkey(dist1) & 0xFFFFFF80u) | (unsigned)(col1-1)) : 0xFFFFFFFFu;
      unsigned key = q0 < q1 ? q0 : q1;
      unsigned kmin = (unsigned)__builtin_amdgcn_readlane((int)dpp_min64(key), 63);
      int j1 = (int)(kmin & 127u) + 1;
      int owner = (j1-1) & 63, slot = (j1-1) >> 6;   // wave-uniform (SGPR)
      float dsel  = slot ? dist1 : dist0;
      int   psel  = slot ? rp1   : rp0;
      float pusel = slot ? rpu1  : rpu0;
      // dynamic-SGPR readlane: exact broadcast, no DS latency
      float delta = __uint_as_float((unsigned)__builtin_amdgcn_readlane(__float_as_int(dsel), owner));
      int   i0    = __builtin_amdgcn_readlane(psel, owner);
      float pu    = __uint_as_float((unsigned)__builtin_amdgcn_readlane(__float_as_int(pusel), owner));
      used0 |= (j1 == col0);
      used1 |= (j1 == col1);
      if (i0 == 0){ j_end = j1; delta_end = delta; break; }
      float bse = delta - pu;
      float2 cc = Cm2[(i0 - 1)*64 + lane];           // one ds_read_b64
      float nd0 = bse + cc.x - v0;
      float nd1 = bse + cc.y - v1;
      if (a0 && !used0 && (nd0 < dist0)){ dist0 = nd0; way0 = j1; }
      if (a1 && !used1 && (nd1 < dist1)){ dist1 = nd1; way1 = j1; }
    }
    if (used0){ float adj = delta_end - dist0; v0 -= adj; u_l[rp0] = rpu0 + adj; }
    if (used1){ float adj = delta_end - dist1; v1 -= adj; u_l[rp1] = rpu1 + adj; }
    if (lane == 0) u_l[irow] = delta_end;
    if (a0) way_l[col0] = way0;
    if (a1) way_l[col1] = way1;
    int j0 = j_end;
    while (true){
      int jw = way_l[j0];
      int pr = p_l[jw];
      int pw = (jw == 0) ? irow : pr;
      if (lane == 0) p_l[j0] = pw;
      if (jw == 0) break;
      j0 = jw;
    }
  }

  __syncthreads();
  float acc = 0.f;
  if (a0) acc += Cm2[(p_l[col0]-1)*64 + lane].x;
  if (a1) acc += Cm2[(p_l[col1]-1)*64 + lane].y;
  acc = wave_sum(acc);
  if (lane == 0){
    atomicAdd(sg_acc, (double)(-acc));   // max-assignment value of A
    atomicAdd(si_acc, k);
  }
  finish_block(sd_acc, sg_acc, si_acc, cnt, out, lane);
}

extern "C" void kernel_launch(void* const* d_in, const int* in_sizes, int n_in,
                              void* d_out, int out_size, void* d_ws, size_t ws_size,
                              hipStream_t stream) {
  const float* logits = (const float*)d_in[0];
  const int*   gt     = (const int*)d_in[1];
  const int*   types  = (const int*)d_in[2];
  const unsigned char* maskraw = (const unsigned char*)d_in[3];
  float* out = (float*)d_out;

  // accumulators: sd (double), sg (double), si (int), cnt (unsigned)
  double*   sd  = (double*)d_ws;
  double*   sg  = sd + 1;
  int*      si  = (int*)(sg + 1);
  unsigned* cnt = (unsigned*)(si + 1);
  hipMemsetAsync(d_ws, 0, 32, stream);

  k_main<<<NBLK, 64, 0, stream>>>(logits, types, gt, maskraw, sd, sg, si, cnt, out);
}

// Round 4
// 430.133 us; speedup vs baseline: 1.1579x; 1.1579x over previous
//
#include <hip/hip_runtime.h>
#include <math.h>

#define BB 16
#define NN 1024
#define VV 4096
#define TT 8
#define NG (BB*TT)   // 128 groups
#define KMAX 124     // max group size; Binomial(1024,1/16): mean 64, sigma 7.75 -> ~8 sigma
#define STRIDE 124

__device__ __forceinline__ float wave_sum(float v){
  #pragma unroll
  for (int off = 32; off; off >>= 1) v += __shfl_down(v, off);
  return v;
}

// monotone float <-> uint key (finite values)
__device__ __forceinline__ unsigned fkey(float f){
  unsigned b = __float_as_uint(f);
  return b ^ ((unsigned)((int)b >> 31) | 0x80000000u);
}
__device__ __forceinline__ float inv_fkey(unsigned u){
  unsigned b = (u & 0x80000000u) ? (u ^ 0x80000000u) : ~u;
  return __uint_as_float(b);
}

// 64-lane min-reduction via DPP (VALU-only). Result valid in lane 63.
__device__ __forceinline__ unsigned dpp_min64(unsigned x){
  unsigned t;
  t = (unsigned)__builtin_amdgcn_update_dpp(-1, (int)x, 0x111, 0xF, 0xF, false); x = x < t ? x : t;
  t = (unsigned)__builtin_amdgcn_update_dpp(-1, (int)x, 0x112, 0xF, 0xF, false); x = x < t ? x : t;
  t = (unsigned)__builtin_amdgcn_update_dpp(-1, (int)x, 0x114, 0xF, 0xF, false); x = x < t ? x : t;
  t = (unsigned)__builtin_amdgcn_update_dpp(-1, (int)x, 0x118, 0xF, 0xF, false); x = x < t ? x : t;
  t = (unsigned)__builtin_amdgcn_update_dpp(-1, (int)x, 0x142, 0xF, 0xF, false); x = x < t ? x : t;
  t = (unsigned)__builtin_amdgcn_update_dpp(-1, (int)x, 0x143, 0xF, 0xF, false); x = x < t ? x : t;
  return x;
}

// ---------------------------------------------------------------------------
// Fused kernel (R1 structure, best measured 431.4 us): blocks [0, NG) run the
// per-group LAP (Jonker-Volgenant, one wave per block); blocks [NG, NG+BB*NN)
// compute per-row logsumexp over V=4096 (64-lane, register-resident row, no
// LDS use beyond the static reservation). jv blocks dispatch first; the 16384
// memory-bound lse blocks fill the CUs the 128 latency-bound jv blocks leave
// idle. This round's single change vs R1: s_setprio(1) on jv waves so their
// serial pop-chain wins issue arbitration against co-resident lse waves (T5
// wave-role-split regime). R3's bundle (barrier removal + float2 relayout +
// atomic epilogue) regressed jv ~165->230 us and is fully reverted.
// Mask layout is probed per-block (bool 1B vs int32 4B). Unmasked rows write
// lse=0 (d_ws is poisoned by the harness, can't rely on zeros).
__global__ __launch_bounds__(64) void k_main(const float* __restrict__ logits,
                                             const int* __restrict__ types,
                                             const int* __restrict__ gt,
                                             const unsigned char* __restrict__ raw,
                                             int* __restrict__ kcnt,
                                             float* __restrict__ gval,
                                             float* __restrict__ lse){
  int lane = threadIdx.x;

  if (blockIdx.x >= NG){
    // ------------------------- LSE path -------------------------
    int row = blockIdx.x - NG;
    uchar4 pv = ((const uchar4*)raw)[lane];            // bytes 0..255 of mask
    bool bool_layout = (__ballot((pv.y | pv.z | pv.w) != 0) != 0ull);
    int mv = bool_layout ? (int)raw[row] : ((const int*)raw)[row];
    if (mv == 0){ if (lane == 0) lse[row] = 0.f; return; }

    const float4* x = (const float4*)(logits + (size_t)row * VV);
    float4 v[16];
    #pragma unroll
    for (int i = 0; i < 16; i++) v[i] = x[lane + 64*i];   // coalesced, 16 in flight
    float m = -INFINITY;
    #pragma unroll
    for (int i = 0; i < 16; i++)
      m = fmaxf(m, fmaxf(fmaxf(v[i].x, v[i].y), fmaxf(v[i].z, v[i].w)));
    #pragma unroll
    for (int off = 32; off; off >>= 1) m = fmaxf(m, __shfl_xor(m, off));
    float s = 0.f;
    #pragma unroll
    for (int i = 0; i < 16; i++)
      s += __expf(v[i].x - m) + __expf(v[i].y - m)
         + __expf(v[i].z - m) + __expf(v[i].w - m);
    #pragma unroll
    for (int off = 32; off; off >>= 1) s += __shfl_xor(s, off);
    if (lane == 0) lse[row] = m + __logf(s);
    return;
  }

  // ------------------------- JV / LAP path -------------------------
  // lapjv init (column reduction + 3x augmenting row reduction) + Dijkstra
  // SAP for remaining free rows. One wave per block; lane owns cols
  // {lane+1, lane+65} (1-based). All phases maintain dual feasibility.
  __builtin_amdgcn_s_setprio(1);       // jv is the k_main span: win arbitration
  __shared__ float Cm[KMAX*STRIDE];    // 61504 B
  __shared__ float u_l[KMAX+1];        // row potentials (rows 1..k); [0] scratch
  __shared__ int   p_l[KMAX+1];        // col -> row (1-based; 0 = free)
  __shared__ int   way_l[KMAX+1];      // idx staging, then scan predecessors
  __shared__ int   rowown[KMAX];       // CR: row -> winning col (-1 free)
  __shared__ int   listA[KMAX];        // gtk staging, then free-row list
  __shared__ int   listB[KMAX];
  int g = blockIdx.x, b = g >> 3, t = g & 7;
  unsigned long long lm = (1ull << lane) - 1ull;

  // ---- inline prep: mask layout probe + ballot compaction ----
  int local = 0;
  const uchar4* r4 = (const uchar4*)raw;
  #pragma unroll
  for (int r = 0; r < 4; r++){ uchar4 u = r4[lane + 64*r]; local |= (u.y | u.z | u.w); }
  bool bool_layout = (__ballot(local != 0) != 0ull);
  const int* rawi = (const int*)raw;
  int base = 0;
  for (int r = 0; r < NN/64; r++){
    int pos = r*64 + lane, o = b*NN + pos;
    int mv = bool_layout ? (int)raw[o] : rawi[o];
    bool pred = (types[o] == t) && (mv != 0);
    unsigned long long ball = __ballot(pred);
    int dst = base + __popcll(ball & lm);
    if (pred && dst < KMAX){ way_l[dst] = pos; listA[dst] = gt[o]; }
    base += __popcll(ball);
  }
  int k = (base > KMAX) ? KMAX : base;
  if (lane == 0) kcnt[g] = k;
  if (k == 0){ if (lane == 0) gval[g] = 0.f; return; }

  int col0 = lane + 1, col1 = lane + 65;
  bool a0 = (col0 <= k), a1 = (col1 <= k);
  int gc0 = a0 ? listA[lane]      : 0;   // same-wave LDS: in-order DS pipe
  int gc1 = a1 ? listA[lane + 64] : 0;

  u_l[col0] = 0.f; p_l[col0] = 0;
  if (col1 <= KMAX){ u_l[col1] = 0.f; p_l[col1] = 0; }
  if (lane == 0){ u_l[0] = 0.f; p_l[0] = 0; }
  rowown[lane] = -1;
  if (lane + 64 < KMAX) rowown[lane+64] = -1;
  __syncthreads();

  // ---- staging: 8-row software pipeline (16 gathers in flight; L3-hot) ----
  const size_t rowbase = (size_t)b * NN;
  for (int i = 0; i < k; i += 8){
    float xs0[8], xs1[8]; int rr[8];
    #pragma unroll
    for (int s = 0; s < 8; s++){
      int r = i + s; r = (r < k) ? r : (k - 1); rr[s] = r;
      const float* q = logits + (rowbase + way_l[r]) * VV;
      xs0[s] = q[gc0]; xs1[s] = q[gc1];
    }
    #pragma unroll
    for (int s = 0; s < 8; s++){
      Cm[rr[s]*STRIDE + lane]      = -xs0[s];
      Cm[rr[s]*STRIDE + 64 + lane] = -xs1[s];
    }
  }
  __syncthreads();

  // ---- column reduction: v[j] = min_i C[i][j]; assign argmin row if free ----
  float v0 = 0.f, v1 = 0.f;
  int ra0 = -1, ra1 = -1;
  if (a0){ float m = INFINITY; int rm = 0;
    for (int i = 0; i < k; i++){ float c = Cm[i*STRIDE + lane]; if (c < m){ m = c; rm = i; } }
    v0 = m; ra0 = rm; }
  if (a1){ float m = INFINITY; int rm = 0;
    for (int i = 0; i < k; i++){ float c = Cm[i*STRIDE + 64 + lane]; if (c < m){ m = c; rm = i; } }
    v1 = m; ra1 = rm; }
  if (a0){ if (atomicCAS(&rowown[ra0], -1, col0) == -1) p_l[col0] = ra0 + 1; }
  if (a1){ if (atomicCAS(&rowown[ra1], -1, col1) == -1) p_l[col1] = ra1 + 1; }
  __syncthreads();

  // free-row list
  bool f0 = (lane < k)    && (rowown[lane]    == -1);
  bool f1 = (lane+64 < k) && (rowown[lane+64] == -1);
  unsigned long long B0 = __ballot(f0), B1 = __ballot(f1);
  int n0 = __popcll(B0);
  if (f0) listA[__popcll(B0 & lm)]      = lane + 1;   // rows 1-based
  if (f1) listA[n0 + __popcll(B1 & lm)] = lane + 65;
  int nCur = n0 + __popcll(B1);
  __syncthreads();

  // ---- augmenting row reduction, 3 passes ----
  int* curL = listA; int* nxtL = listB;
  for (int pass = 0; pass < 3; pass++){
    int nNxt = 0;
    for (int fr = 0; fr < nCur; fr++){
      int row = curL[fr];                       // wave-uniform
      int off = (row - 1) * STRIDE;
      float rc0 = a0 ? (Cm[off + lane]      - v0) : INFINITY;
      float rc1 = a1 ? (Cm[off + 64 + lane] - v1) : INFINITY;
      unsigned k0 = fkey(rc0), k1 = fkey(rc1);
      unsigned kk = k0 < k1 ? k0 : k1;
      unsigned m1 = (unsigned)__builtin_amdgcn_readlane((int)dpp_min64(kk), 63);
      int cand = (k0 == m1) ? col0 : ((k1 == m1) ? col1 : 0);
      unsigned long long bl1 = __ballot(cand != 0);
      int ow1 = __ffsll(bl1) - 1;
      int j1 = __builtin_amdgcn_readlane(cand, ow1);
      float u1 = inv_fkey(m1);
      unsigned k0b = (col0 == j1) ? 0xFFFFFFFFu : k0;
      unsigned k1b = (col1 == j1) ? 0xFFFFFFFFu : k1;
      unsigned kkb = k0b < k1b ? k0b : k1b;
      unsigned m2 = (unsigned)__builtin_amdgcn_readlane((int)dpp_min64(kkb), 63);
      float u2 = inv_fkey(m2);
      int jt = j1;
      if (u1 < u2){
        if (col0 == j1) v0 -= (u2 - u1);
        if (col1 == j1) v1 -= (u2 - u1);
      } else {
        int own1 = p_l[j1];
        if (own1 != 0){
          int cand2 = (k0b == m2) ? col0 : ((k1b == m2) ? col1 : 0);
          unsigned long long bl2 = __ballot(cand2 != 0);
          int ow2 = __ffsll(bl2) - 1;
          jt = __builtin_amdgcn_readlane(cand2, ow2);
        }
      }
      int iprev = p_l[jt];                      // wave-uniform
      if (lane == 0){ p_l[jt] = row; u_l[row] = u2; }
      if (iprev != 0){ if (lane == 0) nxtL[nNxt] = iprev; nNxt++; }
      __syncthreads();
    }
    int* tmp = curL; curL = nxtL; nxtL = tmp;
    nCur = nNxt;
  }

  // ---- Dijkstra shortest augmenting path for remaining free rows ----
  for (int fr = 0; fr < nCur; fr++){
    int irow = curL[fr];
    int rp0 = a0 ? p_l[col0] : 0;
    int rp1 = a1 ? p_l[col1] : 0;
    float rpu0 = (rp0 > 0) ? u_l[rp0] : 0.f;
    float rpu1 = (rp1 > 0) ? u_l[rp1] : 0.f;
    int off = (irow - 1) * STRIDE;
    float dist0 = a0 ? (Cm[off + lane]      - v0) : INFINITY;
    float dist1 = a1 ? (Cm[off + 64 + lane] - v1) : INFINITY;
    int way0 = 0, way1 = 0;
    bool used0 = false, used1 = false;
    int j_end; float delta_end;
    while (true){
      unsigned q0 = (a0 && !used0) ? ((fkey(dist0) & 0xFFFFFF80u) | (unsigned)(col0-1)) : 0xFFFFFFFFu;
      unsigned q1 = (a1 && !used1) ? ((fkey(dist1) & 0xFFFFFF80u) | (unsigned)(col1-1)) : 0xFFFFFFFFu;
      unsigned key = q0 < q1 ? q0 : q1;
      unsigned kmin = (unsigned)__builtin_amdgcn_readlane((int)dpp_min64(key), 63);
      int j1 = (int)(kmin & 127u) + 1;
      int owner = (j1-1) & 63, slot = (j1-1) >> 6;   // wave-uniform (SGPR)
      float dsel  = slot ? dist1 : dist0;
      int   psel  = slot ? rp1   : rp0;
      float pusel = slot ? rpu1  : rpu0;
      // dynamic-SGPR readlane: exact broadcast, no DS latency
      float delta = __uint_as_float((unsigned)__builtin_amdgcn_readlane(__float_as_int(dsel), owner));
      int   i0    = __builtin_amdgcn_readlane(psel, owner);
      float pu    = __uint_as_float((unsigned)__builtin_amdgcn_readlane(__float_as_int(pusel), owner));
      used0 |= (j1 == col0);
      used1 |= (j1 == col1);
      if (i0 == 0){ j_end = j1; delta_end = delta; break; }
      float bse = delta - pu;
      int o2 = (i0 - 1) * STRIDE;
      float c0 = Cm[o2 + lane];
      float c1 = Cm[o2 + 64 + lane];
      float nd0 = bse + c0 - v0;
      float nd1 = bse + c1 - v1;
      if (a0 && !used0 && (nd0 < dist0)){ dist0 = nd0; way0 = j1; }
      if (a1 && !used1 && (nd1 < dist1)){ dist1 = nd1; way1 = j1; }
    }
    if (used0){ float adj = delta_end - dist0; v0 -= adj; u_l[rp0] = rpu0 + adj; }
    if (used1){ float adj = delta_end - dist1; v1 -= adj; u_l[rp1] = rpu1 + adj; }
    if (lane == 0) u_l[irow] = delta_end;
    if (a0) way_l[col0] = way0;
    if (a1) way_l[col1] = way1;
    __syncthreads();
    int j0 = j_end;
    while (true){
      int jw = way_l[j0];
      int pr = p_l[jw];
      int pw = (jw == 0) ? irow : pr;
      if (lane == 0) p_l[j0] = pw;
      if (jw == 0) break;
      j0 = jw;
    }
    __syncthreads();
  }

  __syncthreads();
  float acc = 0.f;
  if (a0) acc += Cm[(p_l[col0]-1)*STRIDE + lane];
  if (a1) acc += Cm[(p_l[col1]-1)*STRIDE + 64 + lane];
  acc = wave_sum(acc);
  __builtin_amdgcn_s_setprio(0);
  if (lane == 0) gval[g] = -acc;       // max-assignment value of A
}

// ---------------------------------------------------------------------------
// loss = (sum lse - sum_g gval) / sum_g k   (unmasked rows hold lse=0)
__global__ __launch_bounds__(256) void k_final(const float* __restrict__ lse,
                                               const int* __restrict__ kcnt,
                                               const float* __restrict__ gval,
                                               float* __restrict__ out){
  __shared__ double sd[256];
  __shared__ double sg[256];
  __shared__ int    si[256];
  int tid = threadIdx.x;
  double s = 0.0, gs = 0.0; int c = 0;
  for (int i = tid; i < BB*NN; i += 256) s += (double)lse[i];
  for (int i = tid; i < NG; i += 256){ gs += (double)gval[i]; c += kcnt[i]; }
  sd[tid] = s; sg[tid] = gs; si[tid] = c;
  __syncthreads();
  for (int off = 128; off; off >>= 1){
    if (tid < off){ sd[tid] += sd[tid+off]; sg[tid] += sg[tid+off]; si[tid] += si[tid+off]; }
    __syncthreads();
  }
  if (tid == 0) out[0] = (float)((sd[0] - sg[0]) / (double)si[0]);
}

extern "C" void kernel_launch(void* const* d_in, const int* in_sizes, int n_in,
                              void* d_out, int out_size, void* d_ws, size_t ws_size,
                              hipStream_t stream) {
  const float* logits = (const float*)d_in[0];
  const int*   gt     = (const int*)d_in[1];
  const int*   types  = (const int*)d_in[2];
  const unsigned char* maskraw = (const unsigned char*)d_in[3];
  float* out = (float*)d_out;

  char* w = (char*)d_ws;
  float* lse  = (float*)w;  w += (size_t)BB*NN*4;
  int*   kcnt = (int*)w;    w += 1024;
  float* gval = (float*)w;  w += 1024;

  k_main <<<NG + BB*NN, 64, 0, stream>>>(logits, types, gt, maskraw, kcnt, gval, lse);
  k_final<<<1, 256, 0, stream>>>(lse, kcnt, gval, out);
}